// Round 1
// baseline (275.294 us; speedup 1.0000x reference)
//
#include <hip/hip_runtime.h>
#include <hip/hip_bf16.h>

// out[t,b,i,e] = x[t,b,i] * W[i,e] + b[e]
// T=8, B=64, D=512, E=256. All fp32.
// rows = T*B*D = 262144; each row is E=256 floats = 64 float4.
// One wave (64 lanes) == one row per float4-chunk: lane e4 handles W[i][e4*4..e4*4+3].

#define D_DIM 512
#define E4 64           // E/4
#define TOTAL4 16777216 // T*B*D*E/4

__global__ __launch_bounds__(256) void dense_embed_kernel(
    const float* __restrict__ x,
    const float4* __restrict__ W,   // (D, E/4)
    const float4* __restrict__ b,   // (E/4)
    float4* __restrict__ out)       // (rows, E/4)
{
    int idx = blockIdx.x * blockDim.x + threadIdx.x;
    const int stride = gridDim.x * blockDim.x;   // multiple of 64 -> e4 invariant

    const int e4 = idx & (E4 - 1);
    const float4 bb = b[e4];

    for (; idx < TOTAL4; idx += stride) {
        const int row = idx >> 6;            // idx / E4
        const int i   = row & (D_DIM - 1);   // row % D
        const float xv = x[row];             // wave-uniform
        const float4 w = W[(i << 6) + e4];   // coalesced, L2-resident after first pass
        float4 o;
        o.x = fmaf(xv, w.x, bb.x);
        o.y = fmaf(xv, w.y, bb.y);
        o.z = fmaf(xv, w.z, bb.z);
        o.w = fmaf(xv, w.w, bb.w);
        out[idx] = o;
    }
}

extern "C" void kernel_launch(void* const* d_in, const int* in_sizes, int n_in,
                              void* d_out, int out_size, void* d_ws, size_t ws_size,
                              hipStream_t stream) {
    const float*  x = (const float*)d_in[0];
    const float4* W = (const float4*)d_in[1];
    const float4* b = (const float4*)d_in[2];
    float4* out = (float4*)d_out;

    // 4096 blocks x 256 threads = 1,048,576 threads; 16 float4 per thread.
    dense_embed_kernel<<<4096, 256, 0, stream>>>(x, W, b, out);
}

// Round 3
// 269.376 us; speedup vs baseline: 1.0220x; 1.0220x over previous
//
#include <hip/hip_runtime.h>
#include <hip/hip_bf16.h>

// out[t,b,i,e] = x[t,b,i] * W[i,e] + b[e]
// T=8, B=64, D=512, E=256, fp32. Output 256 MiB -> pure write-stream kernel.
//
// Each thread owns a fixed (i, e4) pair:
//   - W[i][e4*4..+3] and b[e4*4..+3] register-resident for the whole kernel.
//   - Loop over 32 of the 512 (t,b) rows: wave-uniform x load, 4 FMAs,
//     one coalesced 1 KiB/wave nontemporal store.
// 16 slices x 512 i x 64 e4 = 524288 threads = 2048 blocks of 256.
// Nontemporal stores keep the 256 MiB write-once stream from thrashing L2.

#define DD   512          // D
#define E4   64           // E/4
#define NROW 512          // T*B
#define SLICES 16
#define RPT  (NROW / SLICES)   // 32 rows per thread

typedef float vfloat4 __attribute__((ext_vector_type(4)));  // native vec for nt-store

__global__ __launch_bounds__(256) void dense_embed_kernel(
    const float*  __restrict__ x,    // (NROW, D)
    const float4* __restrict__ W,    // (D, E4)
    const float4* __restrict__ b,    // (E4)
    float4*       __restrict__ out)  // (NROW*D, E4)
{
    const int gtid  = blockIdx.x * 256 + threadIdx.x;
    const int e4    = gtid & (E4 - 1);
    const int i     = (gtid >> 6) & (DD - 1);
    const int slice = gtid >> 15;            // 0..15

    const float4 w  = W[(i << 6) | e4];      // register-resident for all 32 rows
    const float4 bb = b[e4];

    const int r0 = slice * RPT;
    const float* xp = x + r0 * DD + i;                       // wave-uniform addr
    float4* op = out + ((size_t)(r0 * DD + i) << 6) + e4;    // lane-consecutive

    #pragma unroll 4
    for (int k = 0; k < RPT; ++k) {
        const float xv = *xp;                // broadcast within wave
        vfloat4 o;
        o.x = fmaf(xv, w.x, bb.x);
        o.y = fmaf(xv, w.y, bb.y);
        o.z = fmaf(xv, w.z, bb.z);
        o.w = fmaf(xv, w.w, bb.w);
        __builtin_nontemporal_store(o, (vfloat4*)op);  // global_store_dwordx4 nt
        xp += DD;                            // next (t,b) row, same i
        op += (size_t)DD * E4;
    }
}

extern "C" void kernel_launch(void* const* d_in, const int* in_sizes, int n_in,
                              void* d_out, int out_size, void* d_ws, size_t ws_size,
                              hipStream_t stream) {
    const float*  x = (const float*)d_in[0];
    const float4* W = (const float4*)d_in[1];
    const float4* b = (const float4*)d_in[2];
    float4* out = (float4*)d_out;

    dense_embed_kernel<<<2048, 256, 0, stream>>>(x, W, b, out);
}